// Round 7
// baseline (145.303 us; speedup 1.0000x reference)
//
#include <hip/hip_runtime.h>
#include <math.h>

// ---------------------------------------------------------------------------
// TwoDimEquivalent: B=8192 independent nonlinear scans of length T=2048.
// R12: ONE LDS op per step. R11 analysis: ~516 cyc/step = TWO serial DS
// latencies (state-dependent gather + per-step u-read; DS returns in-order
// per wave, so they serialize). Fix: batch the lane's 32-step u window into
// REGISTERS (32 x ds_read_b32, one lgkmcnt wait) at window start; the step
// loop then touches LDS only for the gather.
//  * Wave-autonomous (R11, kept): wave owns 64 rows, private [64][33] LDS
//    buffer, no s_barrier in main loop (one after s_tab fill).
//  * gauss_int: s = delta^2 -> float2 pair-LUT in LDS (one ds_read_b64/step).
//  * 16 chunks x 128 steps, 128-step warmup (bytes/accuracy unchanged).
//  * u prefetch: single G buffer, one-window distance (~10k cyc >> DRAM).
//    Window cycle: READBACK(sb->U regs) -> [flush if pending] -> STAGE(G->sb)
//    -> GLOAD(G, +2 windows) -> 32 reg-fed steps. DS pipe in-order per wave
//    + explicit lgkmcnt fences make the sb reuse race-free.
//  * z: zz[64] regs per 64 steps, flushed through sb (2x 32-col transpose,
//    2-way banks free) at the next window boundary / tail; 128 B row
//    segments, 256 B per flush event.
// History: R5 151.9 (warm 57). R7 2x waves: throughput +2.2x but work
// +1.5x -> latency-bound, concurrency-scalable. R8 LLC-touch: warm
// unchanged -> not read-BW-bound; graded runs ~2.5x-degraded env (DVFS).
// R9 counted barriers: rocprof-cold 147->58. R10 ILP-2: TLP loss regress.
// R11 no-barrier: warm 55 (null) -> two-DS-latency chain theory.
// R12 predict: warm 33-42, graded 90-110; if warm ~50 -> gather IS the
// chain, next = polynomial g(s).
// ---------------------------------------------------------------------------

#define Bsz   8192
#define Tlen  2048
#define TP1   2049
#define NQ    64
#define NG    2049                // scalar g samples, s = j/32 on [0,64]
#define NTAB2 2048                // float2 pair entries (16 KB)
#define INV_H 32.0f
#define CHUNKS 16
#define CLEN  128
#define WARM  128
#define BLOCK 256
#define SIM_GRID (32 * CHUNKS)    // 512: 32 row-blocks(256) x 16 chunks
#define SROW  33                  // staging row stride (floats): banks 2-way

#define WS_TAB 128                // scalar g table offset (floats) in d_ws

// LDS-visibility barrier (after s_tab fill only); vmcnt NOT drained.
__device__ __forceinline__ void bar_nodrain() {
    asm volatile("s_waitcnt lgkmcnt(0)" ::: "memory");
    __builtin_amdgcn_s_barrier();
}
// Intra-wave DS fence: all my ds ops complete; compiler may not reorder.
__device__ __forceinline__ void ds_fence() {
    asm volatile("s_waitcnt lgkmcnt(0)" ::: "memory");
}

// --------------------------- setup: build LUT ------------------------------
__global__ __launch_bounds__(256) void setup_kernel(float* __restrict__ ws,
                                                    float* __restrict__ out) {
    __shared__ float  fx[NQ], fw[NQ];
    __shared__ double inv[NQ + 1];
    const int tid = threadIdx.x;
    if (tid <= NQ) inv[tid] = (tid == 0) ? 0.0 : 1.0 / (double)tid;
    __syncthreads();
    if (tid < NQ) {
        // Newton on P_64: guess err ~3e-4 -> 3 updates reach ~1e-15,
        // 4th pass evaluates pp at converged z (no update).
        double z = cos(3.14159265358979323846 * (tid + 0.75) / (NQ + 0.5));
        double p1 = 1.0, p2 = 0.0, pp = 1.0;
        for (int it = 0; it < 4; ++it) {
            p1 = 1.0; p2 = 0.0;
            for (int j = 1; j <= NQ; ++j) {
                double p3 = p2; p2 = p1;
                p1 = ((2.0 * j - 1.0) * z * p2 - (j - 1.0) * p3) * inv[j];
            }
            pp = NQ * (z * p1 - p2) / (z * z - 1.0);
            if (it < 3) z -= p1 / pp;
        }
        double w  = 2.0 / ((1.0 - z * z) * pp * pp);
        double xs = z * 5.0;                       // node scaled to [-5,5]
        fx[tid] = (float)xs;                       // f32 cast, like reference
        fw[tid] = (float)(w * 5.0 * exp(-0.5 * xs * xs) * 0.3989422804014327);
    }
    __syncthreads();
    const int j = blockIdx.x * 256 + tid;          // grid 32x256 = 8192
    if (j < NG) {                                  // g(s_j), s_j = j/32
        const float d = sqrtf((float)j * (1.0f / INV_H));
        float acc = 0.0f;
        #pragma unroll 8
        for (int q = 0; q < NQ; ++q) {
            float t = tanhf(d * fx[q]);
            acc = fmaf(fw[q], 1.0f - t * t, acc);
        }
        ws[WS_TAB + j] = acc;
    }
    out[(size_t)j * TP1] = 0.0f;                   // z_hist[:,0] = 0
}

// ------------------------------ main scan ----------------------------------
__device__ __forceinline__ float step_one(float uu, float& k1, float& k2,
                                          float& v, const float2* s_tab) {
    float s   = fmaf(k1, k1, fmaf(k2, k2, uu * uu));      // delta^2
    float idx = fminf(s * INV_H, 2046.999f);
    int   i0  = (int)idx;
    float f   = idx - (float)i0;
    float2 g2 = s_tab[i0];                                // the ONE ds op
    float g   = fmaf(f, g2.y - g2.x, g2.x);               // gauss_int
    float gv  = g * v;
    float nk1 = fmaf(k1, fmaf(0.2f, g, 0.8f), 0.10f * gv);
    float nk2 = fmaf(k2, fmaf(0.1f, g, 0.8f), 0.38f * gv);
    v  = fmaf(0.2f, uu - v, v);
    k1 = nk1; k2 = nk2;
    return fmaf(2.8f, nk1, -2.2f * nk2);
}

// Load next window (8 float4 = 8 rows x 128 B coalesced segments)
#define GLOAD(G, t) { _Pragma("unroll")                                       \
    for (int r = 0; r < 8; ++r)                                               \
        G[r] = *(const float4*)(up + (size_t)r * 8 * Tlen + (t)); }

// Stage window into per-wave LDS buffer (32 ds_write_b32, banks 2-way free)
#define STAGE(G) { asm volatile("" ::: "memory");  _Pragma("unroll")          \
    for (int r = 0; r < 8; ++r) {                                             \
        int b8 = (8 * r + srow) * SROW + scol;                                \
        sb[b8] = G[r].x; sb[b8+1] = G[r].y; sb[b8+2] = G[r].z;                \
        sb[b8+3] = G[r].w; }                                                  \
    ds_fence(); }

// Batch the lane's 32-step u window into registers: ONE wait per window.
// Banks (l*33+j)%32 = (l+j)%32 -> 2-way, free. Static U[] indexing (unroll).
#define READBACK() { asm volatile("" ::: "memory"); _Pragma("unroll")         \
    for (int j = 0; j < 32; ++j) U[j] = sb[lbase + j];                        \
    ds_fence(); }

// Flush 64 z-cols for the wave's 64 rows through sb (sb must be free).
// Write banks (l+j)%32 2-way; read banks (2k+rh+col)%32 2-way: free.
#define FLUSH(h) { const int cb = t_out + 1 + 64 * (h);                       \
    _Pragma("unroll") for (int p = 0; p < 2; ++p) {                           \
        asm volatile("" ::: "memory");                                        \
        _Pragma("unroll") for (int j = 0; j < 32; ++j)                        \
            sb[lbase + j] = zz[p * 32 + j];                                   \
        ds_fence();                                                           \
        _Pragma("unroll") for (int kk = 0; kk < 32; ++kk) {                   \
            int row = 2 * kk + rh;                                            \
            out[(size_t)(rowb + row) * TP1 + cb + p * 32 + col] =             \
                sb[row * SROW + col];                                         \
        }                                                                     \
        ds_fence(); } }

__global__ __launch_bounds__(BLOCK, 2) void sim_kernel(const float* __restrict__ u,
                                                       const float* __restrict__ ws,
                                                       float* __restrict__ out) {
    __shared__ float2 s_tab[NTAB2];                // 16 KB pair table
    __shared__ float  s_st[4][64 * SROW];          // 4 x 8.4 KB per-wave bufs
    const int tid = threadIdx.x;
    const int w   = tid >> 6;                      // wave id (4)
    const int l   = tid & 63;                      // lane
    float* sb = s_st[w];

    const int c    = blockIdx.x >> 5;              // chunk id (16)
    const int bb   = blockIdx.x & 31;              // row-block id (32)
    const int rowb = bb * 256 + w * 64;            // wave's first row
    const int t_out   = c * CLEN;                  // first owned step
    const int t_begin = (t_out >= WARM) ? (t_out - WARM) : 0;   // c=0 -> 0

    // staging lane map: lane l covers row srow of each 8-row group,
    // 16 B at float offset scol within the 32-step window
    const int srow = l >> 3;                       // 0..7
    const int scol = (l & 7) * 4;                  // 0,4,...,28
    const float* __restrict__ up = u + (size_t)(rowb + srow) * Tlen + scol;
    const int lbase = l * SROW;

    // Issue the first window FIRST so cold misses start immediately.
    float4 G[8];
    GLOAD(G, t_begin);

    {   // pair-table fill from scalar g[] in ws (coalesced float4 + 1 scalar)
        const float* g = ws + WS_TAB;
        #pragma unroll
        for (int i = 0; i < NTAB2 / (BLOCK * 4); ++i) {   // 2 iters
            int k = (i * BLOCK + tid) * 4;
            float4 a = *(const float4*)(g + k);
            float  b = g[k + 4];
            s_tab[k + 0] = make_float2(a.x, a.y);
            s_tab[k + 1] = make_float2(a.y, a.z);
            s_tab[k + 2] = make_float2(a.z, a.w);
            s_tab[k + 3] = make_float2(a.w, b);
        }
    }
    bar_nodrain();                                 // the ONLY block barrier

    // Prime: sb = window(t_begin), G = window(t_begin+32)
    STAGE(G);
    GLOAD(G, t_begin + 32);

    float k1 = 0.f, k2 = 0.f, v = 0.f;
    float U[32];                                   // register u window

    // ---------------- warmup: 0 or 4 windows, z discarded ----------------
    for (int tb = t_begin; tb < t_out; tb += 32) {
        READBACK();                                // U <- window(tb)
        STAGE(G);                                  // sb <- window(tb+32)
        GLOAD(G, tb + 64);                         // <= t_out+32 <= 1952 ok
        #pragma unroll
        for (int t2 = 0; t2 < 32; ++t2)
            step_one(U[t2], k1, k2, v, s_tab);
    }

    // ---------------- output: 4 windows of 32 steps ----------------
    const int col = l & 31;                        // flush col lane
    const int rh  = l >> 5;                        // flush row half (0/1)
    float zz[64];
    #pragma unroll
    for (int k = 0; k < 4; ++k) {
        const int tb = t_out + 32 * k;
        READBACK();                                // U <- window(tb); sb free
        if (k == 2) FLUSH(0);                      // cols [t_out+1, +65)
        STAGE(G);                                  // sb <- window(tb+32)
        int tn = tb + 64;                          // clamp: tail of c=15
        if (tn > Tlen - 32) tn = Tlen - 32;
        GLOAD(G, tn);
        #pragma unroll
        for (int t2 = 0; t2 < 32; ++t2)
            zz[(k & 1) * 32 + t2] = step_one(U[t2], k1, k2, v, s_tab);
    }
    FLUSH(1);                                      // cols [t_out+65, +129)
}

// ------------------------------ launcher -----------------------------------
extern "C" void kernel_launch(void* const* d_in, const int* in_sizes, int n_in,
                              void* d_out, int out_size, void* d_ws, size_t ws_size,
                              hipStream_t stream) {
    const float* u = (const float*)d_in[0];
    float* out = (float*)d_out;
    float* ws  = (float*)d_ws;                     // needs ~9 KB
    setup_kernel<<<32, 256, 0, stream>>>(ws, out);
    sim_kernel<<<SIM_GRID, BLOCK, 0, stream>>>(u, ws, out);
}